// Round 10
// baseline (174.295 us; speedup 1.0000x reference)
//
#include <hip/hip_runtime.h>
#include <hip/hip_bf16.h>
#include <math.h>

typedef __attribute__((ext_vector_type(8))) __bf16 bf16x8;
typedef __attribute__((ext_vector_type(4))) float f32x4;

__device__ __forceinline__ float sigmoid_f(float v) {
  return __builtin_amdgcn_rcpf(1.f + __expf(-v));
}
__device__ __forceinline__ float tanh_f(float z) {
  float az = fabsf(z);
  float e = __expf(-2.f * az);
  float t = (1.f - e) * __builtin_amdgcn_rcpf(1.f + e);
  return copysignf(t, z);
}
__device__ __forceinline__ bf16x8 cvt8(float4 a, float4 b) {
  bf16x8 r;
  r[0] = (__bf16)a.x; r[1] = (__bf16)a.y; r[2] = (__bf16)a.z; r[3] = (__bf16)a.w;
  r[4] = (__bf16)b.x; r[5] = (__bf16)b.y; r[6] = (__bf16)b.z; r[7] = (__bf16)b.w;
  return r;
}

// Pack W_x/W_h fp32 -> bf16 into 12 half-matrix blocks of 16KB, index (ch*6+m).
// m-order pairs matrices by A-operand so each 32KB stage-unit is consecutive:
//   m: 0 Wx_r, 1 Wx_h, 2 Wh_r, 3 Wh_h, 4 Wx_u, 5 Wh_u
// Stage-unit p (0..2) of col-half ch = 32KB at wp + ch*49152 + p*16384.
// 16B chunk c2 = (nt*4+kt)*64 + lane holds
//   W[ro + ch*64 + nt*16 + (lane&15)][kt*32 + (lane>>4)*8 .. +7].
// global_load_lds staging (wave-uniform base + lane*16) lands exactly where the
// ds_read_b128 B-frag reads expect it: both wave-linear, 0 bank conflicts.
__global__ void pack_weights_kernel(const float* __restrict__ Wx,
                                    const float* __restrict__ Wh,
                                    unsigned short* __restrict__ wp) {
  int t = blockIdx.x * 256 + threadIdx.x;
  if (t >= 12288) return;          // 2 halves * 6 matrices * 1024 chunks
  int ch = t / 6144;
  int r  = t - ch * 6144;
  int m  = r >> 10;
  int c2 = r & 1023;
  int nt = c2 >> 8;
  int kt = (c2 >> 6) & 3;
  int lane = c2 & 63;
  const float* src; int ro;
  switch (m) {
    case 0: src = Wx; ro = 128; break;   // Wx_r
    case 1: src = Wx; ro = 256; break;   // Wx_h
    case 2: src = Wh; ro = 128; break;   // Wh_r
    case 3: src = Wh; ro = 256; break;   // Wh_h
    case 4: src = Wx; ro = 0;   break;   // Wx_u
    default: src = Wh; ro = 0;  break;   // Wh_u
  }
  const float* p = src + (ro + ch * 64 + nt * 16 + (lane & 15)) * 128
                       + kt * 32 + (lane >> 4) * 8;
  *(bf16x8*)(wp + t * 8) = cvt8(*(const float4*)p, *(const float4*)(p + 4));
}

// 256 threads = 4 waves, wave owns 16 rows (block: 64 rows). SINGLE-buffered
// 32KB stage units (one A-operand pair) -> 6 vmcnt(0) drains per block and
// only 32KB LDS + ~96 VGPR -> 4 blocks/CU co-resident: cross-block stagger
// hides the drains (effective serial drains ~1.5/block vs r3's 3, r6's 3.5).
__global__ __launch_bounds__(256, 4) void augru_kernel(
    const float* __restrict__ x, const float* __restrict__ hp,
    const float* __restrict__ att, const unsigned short* __restrict__ wp,
    const float* __restrict__ bx, const float* __restrict__ bh,
    float* __restrict__ out) {
  __shared__ __align__(16) unsigned short wlds[16384];  // 32 KB, single buffer
  const int tid  = threadIdx.x;
  const int wave = tid >> 6;
  const int lane = tid & 63;
  const int quad = lane >> 4;
  const int l15  = lane & 15;
  const int rb   = blockIdx.x * 64 + wave * 16;  // this wave's 16 rows
  const int par  = blockIdx.x & 1;               // col-half processing order

  // stage unit s (s=0..5): col-half ch = par^(s>=3), pair p = s%3. 32KB,
  // 8 rounds x 256 threads x 16B, wave-linear.
  auto stage = [&](int s) {
    int ch = par ^ (s >= 3 ? 1 : 0);
    const unsigned short* base = wp + ch * 49152 + (s % 3) * 16384;
#pragma unroll
    for (int i = 0; i < 8; ++i) {
      const unsigned short* g = base + (i * 256 + tid) * 8;
      unsigned short* l = &wlds[(i * 256 + wave * 64) * 8];  // HW adds lane*16B
      __builtin_amdgcn_global_load_lds(
          (const __attribute__((address_space(1))) void*)g,
          (__attribute__((address_space(3))) void*)l, 16, 0, 0);
    }
  };

  stage(0);  // in flight while we build xf A-fragments

  // A-fragments: A[m=l15][k=quad*8+j] per 16x16x32 K-tile.
  // xf up front (phase 0 uses only xf); hf deferred into unit A's gemms.
  bf16x8 xf[4], hf[4];
  {
    const float* xr = x + (rb + l15) * 128;
#pragma unroll
    for (int kt = 0; kt < 4; ++kt) {
      int off = kt * 32 + quad * 8;
      xf[kt] = cvt8(*(const float4*)(xr + off), *(const float4*)(xr + off + 4));
    }
  }
  float atts[4];
#pragma unroll
  for (int r = 0; r < 4; ++r) atts[r] = att[rb + quad * 4 + r];

  f32x4 accR[4], accH[4], keep[4];

  // one half-matrix gemm: 16 ds_read_b128 + 16 MFMA, wave-linear (0 conflicts)
  auto gemm = [&](int j, const bf16x8 (&af)[4], f32x4 (&acc)[4]) {
#pragma unroll
    for (int nt = 0; nt < 4; ++nt)
#pragma unroll
      for (int kt = 0; kt < 4; ++kt) {
        bf16x8 bfrag = *(const bf16x8*)&wlds[j * 8192 + ((nt * 4 + kt) * 64 + lane) * 8];
        acc[nt] = __builtin_amdgcn_mfma_f32_16x16x32_bf16(af[kt], bfrag, acc[nt], 0, 0, 0);
      }
  };
  auto drain = [&]() {
    asm volatile("s_waitcnt vmcnt(0)" ::: "memory");
    __syncthreads();
  };

  drain();  // unit-0 weights + xf resident

#pragma unroll 1
  for (int h = 0; h < 2; ++h) {
    const int s0 = h * 3;
    const int cb = (par ^ h) * 64;  // column base
    float br[4], bhh[4], bxh[4], bu[4];
#pragma unroll
    for (int nt = 0; nt < 4; ++nt) {
      int col = cb + nt * 16 + l15;
      br[nt]  = bx[128 + col] + bh[128 + col];
      bhh[nt] = bh[256 + col];
      bxh[nt] = bx[256 + col];
      bu[nt]  = bx[col] + bh[col];
    }
#pragma unroll
    for (int nt = 0; nt < 4; ++nt) { accR[nt] = (f32x4)0.f; accH[nt] = (f32x4)0.f; }

    // --- unit A: {Wx_r, Wx_h} (xf only; hf loads issued under these gemms)
    gemm(0, xf, accR);
    if (h == 0) {
      const float* hr = hp + (rb + l15) * 128;
#pragma unroll
      for (int kt = 0; kt < 4; ++kt) {
        int off = kt * 32 + quad * 8;
        hf[kt] = cvt8(*(const float4*)(hr + off), *(const float4*)(hr + off + 4));
      }
    }
    gemm(1, xf, accH);
    __syncthreads();      // WAR: all waves done reading unit A
    stage(s0 + 1);        // {Wh_r, Wh_h}; drain covered by cross-block stagger
    drain();

    // --- unit B: {Wh_r, Wh_h} -> r-gate, then h_tilde
    gemm(0, hf, accR);    // accR = x.Wx_r + h.Wh_r
#pragma unroll
    for (int nt = 0; nt < 4; ++nt)
#pragma unroll
      for (int r = 0; r < 4; ++r) {
        keep[nt][r] = sigmoid_f(accR[nt][r] + br[nt]);
        accR[nt][r] = 0.f;
      }
    gemm(1, hf, accR);    // accR = h.Wh_h
    __syncthreads();      // WAR: all waves done reading unit B
    stage(s0 + 2);        // {Wx_u, Wh_u}
    // drain-covering math: h_tilde = tanh(x.Wx_h + bx_h + r*(h.Wh_h + bh_h))
#pragma unroll
    for (int nt = 0; nt < 4; ++nt)
#pragma unroll
      for (int r = 0; r < 4; ++r) {
        keep[nt][r] = tanh_f(accH[nt][r] + bxh[nt] + keep[nt][r] * (accR[nt][r] + bhh[nt]));
        accR[nt][r] = 0.f;
      }
    drain();

    // --- unit C: {Wx_u, Wh_u} -> u, blend, store this col-half
    gemm(0, xf, accR);
    float h0[4][4];       // exact fp32 h_prev for blend; lands under 2nd gemm
#pragma unroll
    for (int nt = 0; nt < 4; ++nt)
#pragma unroll
      for (int r = 0; r < 4; ++r)
        h0[nt][r] = hp[(rb + quad * 4 + r) * 128 + cb + nt * 16 + l15];
    gemm(1, hf, accR);
    if (h == 0) {
      __syncthreads();    // WAR: all waves done reading unit C
      stage(3);           // second col-half's {Wx_r, Wx_h}
    }
#pragma unroll
    for (int nt = 0; nt < 4; ++nt) {
      int col = cb + nt * 16 + l15;
#pragma unroll
      for (int r = 0; r < 4; ++r) {
        int row = rb + quad * 4 + r;
        float u  = sigmoid_f(accR[nt][r] + bu[nt]);
        float ua = atts[r] * u;
        out[row * 128 + col] = fmaf(ua, keep[nt][r] - h0[nt][r], h0[nt][r]);
      }
    }
    if (h == 0) drain();
  }
}

extern "C" void kernel_launch(void* const* d_in, const int* in_sizes, int n_in,
                              void* d_out, int out_size, void* d_ws, size_t ws_size,
                              hipStream_t stream) {
  const float* x   = (const float*)d_in[0];
  const float* hpv = (const float*)d_in[1];
  const float* att = (const float*)d_in[2];
  const float* Wx  = (const float*)d_in[3];
  const float* bx  = (const float*)d_in[4];
  const float* Wh  = (const float*)d_in[5];
  const float* bh  = (const float*)d_in[6];
  float* out = (float*)d_out;
  unsigned short* wp = (unsigned short*)d_ws;  // 196,608 B of scratch

  pack_weights_kernel<<<48, 256, 0, stream>>>(Wx, Wh, wp);
  augru_kernel<<<1024, 256, 0, stream>>>(x, hpv, att, wp, bx, bh, out);
}